// Round 1
// baseline (166.213 us; speedup 1.0000x reference)
//
#include <hip/hip_runtime.h>
#include <math.h>

#define NB   8      // batch
#define SEQ  1024   // S_IN == S_OUT
#define DIM  256    // D_IN == D_OUT

static constexpr float LN_EPS_C = 1e-5f;

// ---------------------------------------------------------------------------
// Kernel 1: Zl = x @ M^T, Z = LayerNorm(Zl) * gamma + beta
// grid = SEQ blocks (one per sequence position k), 256 threads (thread = out dim i)
// All 8 batch rows processed together so M is read once per block, not 8x.
// ---------------------------------------------------------------------------
extern "C" __global__ void __launch_bounds__(256)
k_proj_ln(const float* __restrict__ x, const float* __restrict__ M,
          const float* __restrict__ gamma, const float* __restrict__ beta,
          float* __restrict__ Zl, float* __restrict__ Z)
{
    __shared__ float xs[NB][DIM];
    __shared__ float zs[NB][DIM];
    __shared__ float mu_s[NB], rs_s[NB];
    const int k = blockIdx.x;
    const int i = threadIdx.x;

    #pragma unroll
    for (int b = 0; b < NB; ++b)
        xs[b][i] = x[(b*SEQ + k)*DIM + i];
    __syncthreads();

    float acc[NB];
    #pragma unroll
    for (int b = 0; b < NB; ++b) acc[b] = 0.f;

    const float* Mi = M + i*DIM;
    #pragma unroll 4
    for (int j = 0; j < DIM; j += 4) {
        const float4 m4 = *reinterpret_cast<const float4*>(Mi + j);
        #pragma unroll
        for (int b = 0; b < NB; ++b) {
            acc[b] = fmaf(xs[b][j  ], m4.x,
                     fmaf(xs[b][j+1], m4.y,
                     fmaf(xs[b][j+2], m4.z,
                     fmaf(xs[b][j+3], m4.w, acc[b]))));
        }
    }

    #pragma unroll
    for (int b = 0; b < NB; ++b) zs[b][i] = acc[b];
    __syncthreads();

    // LN stats: 32 threads per batch row, shuffle-reduce within the 32-group
    {
        const int b = i >> 5;
        const int l = i & 31;
        float s1 = 0.f, s2 = 0.f;
        #pragma unroll
        for (int q = 0; q < 8; ++q) {
            const float v = zs[b][l*8 + q];
            s1 += v; s2 += v*v;
        }
        #pragma unroll
        for (int m = 16; m >= 1; m >>= 1) {
            s1 += __shfl_xor(s1, m);
            s2 += __shfl_xor(s2, m);
        }
        if (l == 0) {
            const float mu  = s1 * (1.f/DIM);
            const float var = s2 * (1.f/DIM) - mu*mu;
            mu_s[b] = mu;
            rs_s[b] = rsqrtf(var + LN_EPS_C);
        }
    }
    __syncthreads();

    const float g = gamma[i], bt = beta[i];
    #pragma unroll
    for (int b = 0; b < NB; ++b) {
        const int off = (b*SEQ + k)*DIM + i;
        Zl[off] = acc[b];
        Z[off]  = (acc[b] - mu_s[b]) * rs_s[b] * g + bt;
    }
}

// ---------------------------------------------------------------------------
// Kernel 2: T[b,k,i] = sum_j Z[b,k,j] * P[i,j] * cos(2*pi*k / (i*256+j+2))
//           then V = T + Zl, written in place over Z.
// grid = SEQ blocks (one per k), 256 threads (thread = output dim i).
// periods are analytic -> v_rcp + v_fract + v_cos (v_cos takes revolutions).
// ---------------------------------------------------------------------------
extern "C" __global__ void __launch_bounds__(256)
k_gate(const float* __restrict__ P, const float* __restrict__ Zl,
       float* __restrict__ Z /* in: Z, out: V = T + Zl */)
{
    __shared__ float zs[NB][DIM];
    const int k = blockIdx.x;
    const int i = threadIdx.x;

    #pragma unroll
    for (int b = 0; b < NB; ++b)
        zs[b][i] = Z[(b*SEQ + k)*DIM + i];
    __syncthreads();

    float acc[NB];
    #pragma unroll
    for (int b = 0; b < NB; ++b) acc[b] = 0.f;

    const float kf = (float)k;
    const float* Pi = P + i*DIM;
    const float pb = (float)(i*DIM + 2);   // period at j=0

    for (int j4 = 0; j4 < DIM; j4 += 4) {
        const float4 p4 = *reinterpret_cast<const float4*>(Pi + j4);
        float w[4];
        #pragma unroll
        for (int u = 0; u < 4; ++u) {
            float r = kf * __builtin_amdgcn_rcpf(pb + (float)(j4 + u));
            r -= floorf(r);                       // revolutions in [0,1)
            w[u] = __builtin_amdgcn_cosf(r);      // cos(2*pi*r)
        }
        w[0] *= p4.x; w[1] *= p4.y; w[2] *= p4.z; w[3] *= p4.w;
        #pragma unroll
        for (int b = 0; b < NB; ++b) {
            const float4 z4 = *reinterpret_cast<const float4*>(&zs[b][j4]);
            acc[b] = fmaf(z4.x, w[0], fmaf(z4.y, w[1],
                     fmaf(z4.z, w[2], fmaf(z4.w, w[3], acc[b]))));
        }
    }
    __syncthreads();   // everyone done reading zs before we overwrite Z

    #pragma unroll
    for (int b = 0; b < NB; ++b) {
        const int off = (b*SEQ + k)*DIM + i;
        Z[off] = acc[b] + Zl[off];
    }
}

// ---------------------------------------------------------------------------
// Kernel 3: out[b,s,d] = sum_k V[b,k,d] * Linker[k,s]
// Tiled fp32 GEMM: 64(s) x 64(d) tile per block, BK=16, 4x4 register blocking.
// grid = (16, 4, 8), 256 threads.
// ---------------------------------------------------------------------------
#define TS 64
#define TD 64
#define TK 16
extern "C" __global__ void __launch_bounds__(256)
k_linker(const float* __restrict__ L, const float* __restrict__ V,
         float* __restrict__ out)
{
    __shared__ float Ls[TK][TS+4];
    __shared__ float Vs[TK][TD+4];
    const int b  = blockIdx.z;
    const int s0 = blockIdx.x * TS;
    const int d0 = blockIdx.y * TD;
    const int t  = threadIdx.x;
    const int ts = t >> 4, td = t & 15;

    float C[4][4];
    #pragma unroll
    for (int a = 0; a < 4; ++a)
        #pragma unroll
        for (int c = 0; c < 4; ++c) C[a][c] = 0.f;

    const int r0 = t >> 6;    // 0..3
    const int c0 = t & 63;    // 0..63

    for (int k0 = 0; k0 < SEQ; k0 += TK) {
        #pragma unroll
        for (int q = 0; q < 4; ++q) {
            const int r = r0 + 4*q;
            Ls[r][c0] = L[(k0 + r)*SEQ + s0 + c0];
            Vs[r][c0] = V[(b*SEQ + k0 + r)*DIM + d0 + c0];
        }
        __syncthreads();
        #pragma unroll
        for (int kk = 0; kk < TK; ++kk) {
            const float4 la = *reinterpret_cast<const float4*>(&Ls[kk][ts*4]);
            const float4 vb = *reinterpret_cast<const float4*>(&Vs[kk][td*4]);
            const float lav[4] = {la.x, la.y, la.z, la.w};
            const float vbv[4] = {vb.x, vb.y, vb.z, vb.w};
            #pragma unroll
            for (int a = 0; a < 4; ++a)
                #pragma unroll
                for (int c = 0; c < 4; ++c)
                    C[a][c] = fmaf(lav[a], vbv[c], C[a][c]);
        }
        __syncthreads();
    }

    #pragma unroll
    for (int a = 0; a < 4; ++a) {
        const float4 o = make_float4(C[a][0], C[a][1], C[a][2], C[a][3]);
        *reinterpret_cast<float4*>(&out[(b*SEQ + s0 + ts*4 + a)*DIM + d0 + td*4]) = o;
    }
}

// ---------------------------------------------------------------------------
extern "C" void kernel_launch(void* const* d_in, const int* in_sizes, int n_in,
                              void* d_out, int out_size, void* d_ws, size_t ws_size,
                              hipStream_t stream)
{
    const float* x     = (const float*)d_in[0];
    const float* M     = (const float*)d_in[1];
    const float* P     = (const float*)d_in[2];
    const float* L     = (const float*)d_in[3];
    const float* gamma = (const float*)d_in[4];
    const float* beta  = (const float*)d_in[5];
    // d_in[6] = periods, recomputed analytically on device

    float* out = (float*)d_out;
    float* Zl  = (float*)d_ws;                 // [NB,SEQ,DIM] fp32 (8 MB)
    float* Z   = Zl + (size_t)NB*SEQ*DIM;      // [NB,SEQ,DIM] fp32 (8 MB), becomes V

    hipLaunchKernelGGL(k_proj_ln, dim3(SEQ), dim3(256), 0, stream,
                       x, M, gamma, beta, Zl, Z);
    hipLaunchKernelGGL(k_gate, dim3(SEQ), dim3(256), 0, stream, P, Zl, Z);
    hipLaunchKernelGGL(k_linker, dim3(SEQ/TS, DIM/TD, NB), dim3(256), 0, stream,
                       L, Z, out);
}

// Round 3
// 88.865 us; speedup vs baseline: 1.8704x; 1.8704x over previous
//
#include <hip/hip_runtime.h>
#include <math.h>

#define NB   8
#define SEQ  1024
#define DIM  256

static constexpr float LN_EPS_C = 1e-5f;

typedef __bf16 bfx8 __attribute__((ext_vector_type(8)));
typedef __bf16 bfx4 __attribute__((ext_vector_type(4)));
typedef float  f32v4 __attribute__((ext_vector_type(4)));

// async global->LDS, 16B per lane; LDS dest must be wave-uniform base (+lane*16)
__device__ inline void gll16(const void* g, void* l) {
    __builtin_amdgcn_global_load_lds(
        (const __attribute__((address_space(1))) void*)g,
        (__attribute__((address_space(3))) void*)l, 16, 0, 0);
}

// ---------------------------------------------------------------------------
// cast fp32 -> bf16, 4 elems/thread
// ---------------------------------------------------------------------------
__global__ void __launch_bounds__(256)
k_cast(const float* __restrict__ s, __bf16* __restrict__ d)
{
    const int idx = (blockIdx.x * 256 + threadIdx.x) * 4;
    const float4 v = *reinterpret_cast<const float4*>(s + idx);
    bfx4 o;
    o[0] = (__bf16)v.x; o[1] = (__bf16)v.y; o[2] = (__bf16)v.z; o[3] = (__bf16)v.w;
    *reinterpret_cast<bfx4*>(d + idx) = o;
}

// ---------------------------------------------------------------------------
// transpose(+cast) 64x64 tiles: dst[c][r] = (bf16)src[r][c]
// grid (rows/64, cols/64, batches)
// ---------------------------------------------------------------------------
template<typename S>
__global__ void __launch_bounds__(256)
k_trans(const S* __restrict__ src, __bf16* __restrict__ dst,
        int inpitch, int outpitch, long ibs, long obs)
{
    __shared__ __bf16 ts[64][73];
    const long z = blockIdx.z;
    const int r0 = blockIdx.x * 64;
    const int c0 = blockIdx.y * 64;
    const int t  = threadIdx.x;
    const int r  = t >> 2;            // src row 0..63
    const int cb = (t & 3) * 16;      // src col base

    const S* sp = src + z * ibs + (size_t)(r0 + r) * inpitch + c0 + cb;
    if constexpr (sizeof(S) == 4) {   // float source
        #pragma unroll
        for (int u = 0; u < 4; ++u) {
            const float4 v = *reinterpret_cast<const float4*>(sp + u * 4);
            ts[r][cb + u*4 + 0] = (__bf16)v.x;
            ts[r][cb + u*4 + 1] = (__bf16)v.y;
            ts[r][cb + u*4 + 2] = (__bf16)v.z;
            ts[r][cb + u*4 + 3] = (__bf16)v.w;
        }
    } else {                          // bf16 source
        #pragma unroll
        for (int u = 0; u < 2; ++u) {
            const bfx8 v = *reinterpret_cast<const bfx8*>(sp + u * 8);
            #pragma unroll
            for (int e = 0; e < 8; ++e) ts[r][cb + u*8 + e] = v[e];
        }
    }
    __syncthreads();

    const int dl = t >> 2;            // dst row (src col) 0..63
    const int kb = (t & 3) * 16;      // dst col (src row) base
    bfx8 o0, o1;
    #pragma unroll
    for (int e = 0; e < 8; ++e) { o0[e] = ts[kb + e][dl]; o1[e] = ts[kb + 8 + e][dl]; }
    __bf16* dp = dst + z * obs + (size_t)(c0 + dl) * outpitch + r0 + kb;
    *reinterpret_cast<bfx8*>(dp)     = o0;
    *reinterpret_cast<bfx8*>(dp + 8) = o1;
}

// ---------------------------------------------------------------------------
// bf16 MFMA GEMM: C[m][n] = sum_k A[m][k] * Bt[n][k]
// A: [M][KD] row-major bf16;  Bt: [256][KD] row-major bf16 (B transposed)
// C: [M][256] fp32 or bf16.  Tile 64(m) x 64(n) x 64(k), 4 waves.
// LDS linear + XOR-swizzled (16B-chunk ^ row&7) via pre-swizzled gll source.
// ---------------------------------------------------------------------------
template<int KD, bool OBF>
__global__ void __launch_bounds__(256)
k_gemm(const __bf16* __restrict__ A, const __bf16* __restrict__ Bt,
       void* __restrict__ Cp, long bsB, long bsC)
{
    __shared__ __bf16 As[64 * 64];
    __shared__ __bf16 Bs[64 * 64];
    const int m0 = blockIdx.x * 64;
    const int n0 = blockIdx.y * 64;
    const long zb = blockIdx.z;
    const int t = threadIdx.x, l = t & 63, w = t >> 6;
    const __bf16* Bz = Bt + zb * bsB;

    f32v4 acc[4] = {};

    for (int k0 = 0; k0 < KD; k0 += 64) {
        // stage: each wave issues 2 A + 2 B gll instrs (8 rows x 128B each)
        #pragma unroll
        for (int q = 0; q < 2; ++q) {
            const int p  = 2 * w + q;
            const int rr = p * 8 + (l >> 3);         // tile-local row
            const int sc = (l & 7) ^ (l >> 3);       // pre-swizzled source chunk
            gll16(A  + (size_t)(m0 + rr) * KD + k0 + sc * 8, &As[p * 512]);
            gll16(Bz + (size_t)(n0 + rr) * KD + k0 + sc * 8, &Bs[p * 512]);
        }
        __syncthreads();   // drains vmcnt: staged data visible

        #pragma unroll
        for (int ks = 0; ks < 2; ++ks) {
            const int lch = ks * 4 + (l >> 4);       // logical 16B chunk
            const int ph  = ((lch ^ (l & 7)) << 3);  // swizzled elem offset
            const bfx8 a = *reinterpret_cast<const bfx8*>(&As[(16*w + (l & 15)) * 64 + ph]);
            #pragma unroll
            for (int c = 0; c < 4; ++c) {
                const bfx8 b = *reinterpret_cast<const bfx8*>(&Bs[(16*c + (l & 15)) * 64 + ph]);
                acc[c] = __builtin_amdgcn_mfma_f32_16x16x32_bf16(a, b, acc[c], 0, 0, 0);
            }
        }
        __syncthreads();   // all reads done before next stage overwrites
    }

    // C/D layout: col = l&15, row = 4*(l>>4) + reg   [verified mapping]
    const int row0 = m0 + 16 * w + 4 * (l >> 4);
    const int col  = l & 15;
    #pragma unroll
    for (int c = 0; c < 4; ++c) {
        #pragma unroll
        for (int r = 0; r < 4; ++r) {
            const size_t off = (size_t)(row0 + r) * 256 + n0 + 16 * c + col;
            if constexpr (OBF) ((__bf16*)Cp + zb * bsC)[off] = (__bf16)acc[c][r];
            else               ((float*)Cp  + zb * bsC)[off] = acc[c][r];
        }
    }
}

// ---------------------------------------------------------------------------
// K2: LN(Zl) -> gate -> V = T + Zl  (bf16 out)
// block = k (1024), thread = output dim i
// ---------------------------------------------------------------------------
__global__ void __launch_bounds__(256)
k_gate(const __bf16* __restrict__ Zl, const float* __restrict__ P,
       const float* __restrict__ gamma, const float* __restrict__ beta,
       __bf16* __restrict__ V)
{
    __shared__ float zs[NB][DIM];
    __shared__ float mu_s[NB], rs_s[NB];
    const int k = blockIdx.x;
    const int i = threadIdx.x;

    float zlr[NB];
    #pragma unroll
    for (int b = 0; b < NB; ++b) {
        zlr[b] = (float)Zl[(b * SEQ + k) * DIM + i];
        zs[b][i] = zlr[b];
    }
    __syncthreads();

    // LN stats: 32 threads per batch row
    {
        const int b = i >> 5;
        const int l = i & 31;
        float s1 = 0.f, s2 = 0.f;
        #pragma unroll
        for (int q = 0; q < 8; ++q) {
            const float v = zs[b][l * 8 + q];
            s1 += v; s2 += v * v;
        }
        #pragma unroll
        for (int m = 16; m >= 1; m >>= 1) {
            s1 += __shfl_xor(s1, m);
            s2 += __shfl_xor(s2, m);
        }
        if (l == 0) {
            const float mu  = s1 * (1.f / DIM);
            const float var = s2 * (1.f / DIM) - mu * mu;
            mu_s[b] = mu;
            rs_s[b] = rsqrtf(var + LN_EPS_C);
        }
    }
    __syncthreads();

    const float g = gamma[i], bt = beta[i];
    #pragma unroll
    for (int b = 0; b < NB; ++b)
        zs[b][i] = (zlr[b] - mu_s[b]) * rs_s[b] * g + bt;
    __syncthreads();

    float acc[NB];
    #pragma unroll
    for (int b = 0; b < NB; ++b) acc[b] = 0.f;

    const float kf = (float)k;
    const float* Pi = P + i * DIM;
    const float pb = (float)(i * DIM + 2);

    for (int j4 = 0; j4 < DIM; j4 += 4) {
        const float4 p4 = *reinterpret_cast<const float4*>(Pi + j4);
        float wgt[4];
        #pragma unroll
        for (int u = 0; u < 4; ++u) {
            float r = kf * __builtin_amdgcn_rcpf(pb + (float)(j4 + u));
            r -= floorf(r);
            wgt[u] = __builtin_amdgcn_cosf(r);
        }
        wgt[0] *= p4.x; wgt[1] *= p4.y; wgt[2] *= p4.z; wgt[3] *= p4.w;
        #pragma unroll
        for (int b = 0; b < NB; ++b) {
            const float4 z4 = *reinterpret_cast<const float4*>(&zs[b][j4]);
            acc[b] = fmaf(z4.x, wgt[0], fmaf(z4.y, wgt[1],
                     fmaf(z4.z, wgt[2], fmaf(z4.w, wgt[3], acc[b]))));
        }
    }

    #pragma unroll
    for (int b = 0; b < NB; ++b)
        V[(b * SEQ + k) * DIM + i] = (__bf16)(acc[b] + zlr[b]);
}

// ---------------------------------------------------------------------------
extern "C" void kernel_launch(void* const* d_in, const int* in_sizes, int n_in,
                              void* d_out, int out_size, void* d_ws, size_t ws_size,
                              hipStream_t stream)
{
    const float* x     = (const float*)d_in[0];
    const float* M     = (const float*)d_in[1];
    const float* P     = (const float*)d_in[2];
    const float* L     = (const float*)d_in[3];
    const float* gamma = (const float*)d_in[4];
    const float* beta  = (const float*)d_in[5];
    float* out = (float*)d_out;

    char* ws = (char*)d_ws;
    __bf16* xb = (__bf16*)(ws);                                 // 4 MB  [8192][256]
    __bf16* Mb = (__bf16*)(ws + (4u << 20));                    // 128 KB [256][256]
    __bf16* Lt = (__bf16*)(ws + (4u << 20) + (128u << 10));     // 2 MB  [1024 s][1024 k]
    __bf16* Zl = (__bf16*)(ws + (6u << 20) + (128u << 10));     // 4 MB  [8192][256]
    __bf16* V  = (__bf16*)(ws + (10u << 20) + (128u << 10));    // 4 MB  [b][k][d]
    __bf16* Vt = xb;   // alias: xb dead after gemm1            // 4 MB  [b][d][k]

    // prep: casts + L transpose
    hipLaunchKernelGGL(k_cast, dim3(2048), dim3(256), 0, stream, x, xb);
    hipLaunchKernelGGL(k_cast, dim3(64),   dim3(256), 0, stream, M, Mb);
    hipLaunchKernelGGL((k_trans<float>), dim3(16, 16, 1), dim3(256), 0, stream,
                       L, Lt, SEQ, SEQ, 0L, 0L);

    // GEMM1: Zl[row][i] = sum_j x[row][j] * M[i][j]   (M = 8192, K = 256)
    hipLaunchKernelGGL((k_gemm<256, true>), dim3(128, 4, 1), dim3(256), 0, stream,
                       xb, Mb, (void*)Zl, 0L, 0L);

    // K2: LN + gate + residual -> V bf16
    hipLaunchKernelGGL(k_gate, dim3(SEQ), dim3(256), 0, stream, Zl, P, gamma, beta, V);

    // V -> Vt  [b][d][k]
    hipLaunchKernelGGL((k_trans<__bf16>), dim3(16, 4, 8), dim3(256), 0, stream,
                       V, Vt, DIM, SEQ, (long)SEQ * DIM, (long)SEQ * DIM);

    // GEMM2: out[b][s][d] = sum_k Lt[s][k] * Vt[b][d][k]   (M = 1024, K = 1024)
    hipLaunchKernelGGL((k_gemm<1024, false>), dim3(16, 4, 8), dim3(256), 0, stream,
                       Lt, Vt, (void*)out, (long)SEQ * DIM, (long)SEQ * DIM);
}

// Round 4
// 65.379 us; speedup vs baseline: 2.5423x; 1.3592x over previous
//
#include <hip/hip_runtime.h>
#include <math.h>

#define NB   8
#define SEQ  1024
#define DIM  256

static constexpr float LN_EPS_C = 1e-5f;

typedef __bf16 bfx8 __attribute__((ext_vector_type(8)));
typedef __bf16 bfx4 __attribute__((ext_vector_type(4)));
typedef float  f32v4 __attribute__((ext_vector_type(4)));

// async global->LDS, 16B per lane; LDS dest must be wave-uniform base (+lane*16)
__device__ inline void gll16(const void* g, void* l) {
    __builtin_amdgcn_global_load_lds(
        (const __attribute__((address_space(1))) void*)g,
        (__attribute__((address_space(3))) void*)l, 16, 0, 0);
}

// ---------------------------------------------------------------------------
// cast fp32 -> bf16, 4 elems/thread
// ---------------------------------------------------------------------------
__global__ void __launch_bounds__(256)
k_cast(const float* __restrict__ s, __bf16* __restrict__ d)
{
    const int idx = (blockIdx.x * 256 + threadIdx.x) * 4;
    const float4 v = *reinterpret_cast<const float4*>(s + idx);
    bfx4 o;
    o[0] = (__bf16)v.x; o[1] = (__bf16)v.y; o[2] = (__bf16)v.z; o[3] = (__bf16)v.w;
    *reinterpret_cast<bfx4*>(d + idx) = o;
}

// ---------------------------------------------------------------------------
// transpose(+cast) 64x64 tiles: dst[c][r] = (bf16)src[r][c]
// ---------------------------------------------------------------------------
template<typename S>
__global__ void __launch_bounds__(256)
k_trans(const S* __restrict__ src, __bf16* __restrict__ dst,
        int inpitch, int outpitch, long ibs, long obs)
{
    __shared__ __bf16 ts[64][73];
    const long z = blockIdx.z;
    const int r0 = blockIdx.x * 64;
    const int c0 = blockIdx.y * 64;
    const int t  = threadIdx.x;
    const int r  = t >> 2;            // src row 0..63
    const int cb = (t & 3) * 16;      // src col base

    const S* sp = src + z * ibs + (size_t)(r0 + r) * inpitch + c0 + cb;
    if constexpr (sizeof(S) == 4) {
        #pragma unroll
        for (int u = 0; u < 4; ++u) {
            const float4 v = *reinterpret_cast<const float4*>(sp + u * 4);
            ts[r][cb + u*4 + 0] = (__bf16)v.x;
            ts[r][cb + u*4 + 1] = (__bf16)v.y;
            ts[r][cb + u*4 + 2] = (__bf16)v.z;
            ts[r][cb + u*4 + 3] = (__bf16)v.w;
        }
    } else {
        #pragma unroll
        for (int u = 0; u < 2; ++u) {
            const bfx8 v = *reinterpret_cast<const bfx8*>(sp + u * 8);
            #pragma unroll
            for (int e = 0; e < 8; ++e) ts[r][cb + u*8 + e] = v[e];
        }
    }
    __syncthreads();

    const int dl = t >> 2;
    const int kb = (t & 3) * 16;
    bfx8 o0, o1;
    #pragma unroll
    for (int e = 0; e < 8; ++e) { o0[e] = ts[kb + e][dl]; o1[e] = ts[kb + 8 + e][dl]; }
    __bf16* dp = dst + z * obs + (size_t)(c0 + dl) * outpitch + r0 + kb;
    *reinterpret_cast<bfx8*>(dp)     = o0;
    *reinterpret_cast<bfx8*>(dp + 8) = o1;
}

// ---------------------------------------------------------------------------
// bf16 MFMA GEMM: C[m][n] = sum_k A[m][k] * Bt[n][k]   (tile 64x64x64, 4 waves)
// ---------------------------------------------------------------------------
template<int KD, bool OBF>
__global__ void __launch_bounds__(256)
k_gemm(const __bf16* __restrict__ A, const __bf16* __restrict__ Bt,
       void* __restrict__ Cp, long bsB, long bsC)
{
    __shared__ __bf16 As[64 * 64];
    __shared__ __bf16 Bs[64 * 64];
    const int m0 = blockIdx.x * 64;
    const int n0 = blockIdx.y * 64;
    const long zb = blockIdx.z;
    const int t = threadIdx.x, l = t & 63, w = t >> 6;
    const __bf16* Bz = Bt + zb * bsB;

    f32v4 acc[4] = {};

    for (int k0 = 0; k0 < KD; k0 += 64) {
        #pragma unroll
        for (int q = 0; q < 2; ++q) {
            const int p  = 2 * w + q;
            const int rr = p * 8 + (l >> 3);
            const int sc = (l & 7) ^ (l >> 3);
            gll16(A  + (size_t)(m0 + rr) * KD + k0 + sc * 8, &As[p * 512]);
            gll16(Bz + (size_t)(n0 + rr) * KD + k0 + sc * 8, &Bs[p * 512]);
        }
        __syncthreads();

        #pragma unroll
        for (int ks = 0; ks < 2; ++ks) {
            const int lch = ks * 4 + (l >> 4);
            const int ph  = ((lch ^ (l & 7)) << 3);
            const bfx8 a = *reinterpret_cast<const bfx8*>(&As[(16*w + (l & 15)) * 64 + ph]);
            #pragma unroll
            for (int c = 0; c < 4; ++c) {
                const bfx8 b = *reinterpret_cast<const bfx8*>(&Bs[(16*c + (l & 15)) * 64 + ph]);
                acc[c] = __builtin_amdgcn_mfma_f32_16x16x32_bf16(a, b, acc[c], 0, 0, 0);
            }
        }
        __syncthreads();
    }

    const int row0 = m0 + 16 * w + 4 * (l >> 4);
    const int col  = l & 15;
    #pragma unroll
    for (int c = 0; c < 4; ++c) {
        #pragma unroll
        for (int r = 0; r < 4; ++r) {
            const size_t off = (size_t)(row0 + r) * 256 + n0 + 16 * c + col;
            if constexpr (OBF) ((__bf16*)Cp + zb * bsC)[off] = (__bf16)acc[c][r];
            else               ((float*)Cp  + zb * bsC)[off] = acc[c][r];
        }
    }
}

// ---------------------------------------------------------------------------
// Gate via MFMA: block = one k. LN(Zl rows) in LDS, then
// T[b,i] = sum_j Zn[b,j] * (P[i,j]*cos(2*pi*k/p_ij)), V = T + Zl  (bf16)
// W-fragments synthesized per-lane in registers (no LDS for W, no b128 storm).
// 4 waves, wave w owns i-range [64w, 64w+64).
// ---------------------------------------------------------------------------
__global__ void __launch_bounds__(256, 4)
k_gateM(const __bf16* __restrict__ Zl, const __bf16* __restrict__ Pb,
        const float* __restrict__ gamma, const float* __restrict__ beta,
        __bf16* __restrict__ V)
{
    __shared__ __bf16 zraw[8 * 256];    // raw Zl rows (swizzled 16B chunks)
    __shared__ __bf16 znorm[16 * 256];  // LN'd rows; rows 8..15 = 0 (M-pad)
    __shared__ float mu_s[8], rs_s[8];

    const int k = blockIdx.x;
    const int t = threadIdx.x;
    const int l = t & 63, w = t >> 6;

    // ---- stage one 16B chunk per thread: row m = t>>5, chunk ch = t&31 ----
    const int m  = t >> 5;
    const int ch = t & 31;
    const bfx8 zv = *reinterpret_cast<const bfx8*>(Zl + ((size_t)(m * SEQ + k)) * DIM + ch * 8);
    *reinterpret_cast<bfx8*>(&zraw[m * 256 + ((ch ^ m) << 3)]) = zv;

    // zero the M-pad rows of znorm
    bfx8 zz;
    #pragma unroll
    for (int e = 0; e < 8; ++e) zz[e] = (__bf16)0.f;
    *reinterpret_cast<bfx8*>(&znorm[(8 + m) * 256 + ((ch ^ m) << 3)]) = zz;

    // ---- LN stats: 32 threads per row, shuffle reduce ----
    float s1 = 0.f, s2 = 0.f;
    #pragma unroll
    for (int e = 0; e < 8; ++e) { const float v = (float)zv[e]; s1 += v; s2 += v * v; }
    #pragma unroll
    for (int q = 16; q >= 1; q >>= 1) { s1 += __shfl_xor(s1, q); s2 += __shfl_xor(s2, q); }
    if (ch == 0) {
        const float mu  = s1 * (1.f / DIM);
        const float var = s2 * (1.f / DIM) - mu * mu;
        mu_s[m] = mu;
        rs_s[m] = rsqrtf(var + LN_EPS_C);
    }
    __syncthreads();

    // ---- normalized rows -> znorm (bf16, swizzled) ----
    {
        const float mu = mu_s[m], rs = rs_s[m];
        const float4 g0 = *reinterpret_cast<const float4*>(gamma + ch * 8);
        const float4 g1 = *reinterpret_cast<const float4*>(gamma + ch * 8 + 4);
        const float4 b0 = *reinterpret_cast<const float4*>(beta  + ch * 8);
        const float4 b1 = *reinterpret_cast<const float4*>(beta  + ch * 8 + 4);
        const float gv[8] = {g0.x, g0.y, g0.z, g0.w, g1.x, g1.y, g1.z, g1.w};
        const float bv[8] = {b0.x, b0.y, b0.z, b0.w, b1.x, b1.y, b1.z, b1.w};
        bfx8 nv;
        #pragma unroll
        for (int e = 0; e < 8; ++e)
            nv[e] = (__bf16)(((float)zv[e] - mu) * rs * gv[e] + bv[e]);
        *reinterpret_cast<bfx8*>(&znorm[m * 256 + ((ch ^ m) << 3)]) = nv;
    }
    __syncthreads();

    // ---- A-fragments (same for all waves; rows 8..15 zero) ----
    const int mm = l & 15;
    bfx8 af[8];
    #pragma unroll
    for (int ks = 0; ks < 8; ++ks) {
        const int cc = ks * 4 + (l >> 4);
        af[ks] = *reinterpret_cast<const bfx8*>(&znorm[mm * 256 + ((cc ^ (mm & 7)) << 3)]);
    }

    // ---- MFMA with register-synthesized W fragments ----
    const float kf = (float)k;
    const int n0w = w * 64;
    f32v4 acc[4] = {};
    #pragma unroll
    for (int c = 0; c < 4; ++c) {
        const int i = n0w + 16 * c + (l & 15);
        const __bf16* Prow = Pb + (size_t)i * DIM;
        #pragma unroll
        for (int ks = 0; ks < 8; ++ks) {
            const int jb = ks * 32 + (l >> 4) * 8;
            const bfx8 pv = *reinterpret_cast<const bfx8*>(Prow + jb);
            const float pbase = (float)(i * DIM + jb + 2);
            bfx8 wf;
            #pragma unroll
            for (int e = 0; e < 8; ++e) {
                float r = kf * __builtin_amdgcn_rcpf(pbase + (float)e);
                r -= floorf(r);                         // revolutions in [0,1)
                wf[e] = (__bf16)(__builtin_amdgcn_cosf(r) * (float)pv[e]);
            }
            acc[c] = __builtin_amdgcn_mfma_f32_16x16x32_bf16(af[ks], wf, acc[c], 0, 0, 0);
        }
    }

    // ---- epilogue: V[b,k,i] = T + Zl  (C rows 0..7 valid; lanes l>>4 < 2) ----
    const int g = l >> 4;
    if (g < 2) {
        const int col = l & 15;
        #pragma unroll
        for (int c = 0; c < 4; ++c) {
            const int i = n0w + 16 * c + col;
            #pragma unroll
            for (int r = 0; r < 4; ++r) {
                const int b = 4 * g + r;
                const float resid = (float)zraw[b * 256 + (((i >> 3) ^ b) << 3) + (i & 7)];
                V[((size_t)(b * SEQ + k)) * DIM + i] = (__bf16)(acc[c][r] + resid);
            }
        }
    }
}

// ---------------------------------------------------------------------------
extern "C" void kernel_launch(void* const* d_in, const int* in_sizes, int n_in,
                              void* d_out, int out_size, void* d_ws, size_t ws_size,
                              hipStream_t stream)
{
    const float* x     = (const float*)d_in[0];
    const float* M     = (const float*)d_in[1];
    const float* P     = (const float*)d_in[2];
    const float* L     = (const float*)d_in[3];
    const float* gamma = (const float*)d_in[4];
    const float* beta  = (const float*)d_in[5];
    float* out = (float*)d_out;

    char* ws = (char*)d_ws;
    __bf16* xb = (__bf16*)(ws);                                 // 4 MB   [8192][256]
    __bf16* Mb = (__bf16*)(ws + (4u << 20));                    // 128 KB [256][256]
    __bf16* Pb = (__bf16*)(ws + (4u << 20) + (128u << 10));     // 128 KB [256][256]
    __bf16* Lt = (__bf16*)(ws + (4u << 20) + (256u << 10));     // 2 MB   [1024 s][1024 k]
    __bf16* Zl = (__bf16*)(ws + (6u << 20) + (256u << 10));     // 4 MB   [8192][256]
    __bf16* V  = (__bf16*)(ws + (10u << 20) + (256u << 10));    // 4 MB   [b][k][d]
    __bf16* Vt = xb;   // alias: xb dead after gemm1            // 4 MB   [b][d][k]

    // prep: casts + L transpose
    hipLaunchKernelGGL(k_cast, dim3(2048), dim3(256), 0, stream, x, xb);
    hipLaunchKernelGGL(k_cast, dim3(64),   dim3(256), 0, stream, M, Mb);
    hipLaunchKernelGGL(k_cast, dim3(64),   dim3(256), 0, stream, P, Pb);
    hipLaunchKernelGGL((k_trans<float>), dim3(16, 16, 1), dim3(256), 0, stream,
                       L, Lt, SEQ, SEQ, 0L, 0L);

    // GEMM1: Zl[row][i] = sum_j x[row][j] * M[i][j]   (M = 8192, K = 256)
    hipLaunchKernelGGL((k_gemm<256, true>), dim3(128, 4, 1), dim3(256), 0, stream,
                       xb, Mb, (void*)Zl, 0L, 0L);

    // gate: LN + cos-gated reduction via MFMA + residual -> V bf16
    hipLaunchKernelGGL(k_gateM, dim3(SEQ), dim3(256), 0, stream,
                       Zl, Pb, gamma, beta, V);

    // V -> Vt  [b][d][k]
    hipLaunchKernelGGL((k_trans<__bf16>), dim3(16, 4, 8), dim3(256), 0, stream,
                       V, Vt, DIM, SEQ, (long)SEQ * DIM, (long)SEQ * DIM);

    // GEMM2: out[b][s][d] = sum_k Lt[s][k] * Vt[b][d][k]   (M = 1024, K = 1024)
    hipLaunchKernelGGL((k_gemm<1024, false>), dim3(16, 4, 8), dim3(256), 0, stream,
                       Lt, Vt, (void*)out, (long)SEQ * DIM, (long)SEQ * DIM);
}

// Round 5
// 61.983 us; speedup vs baseline: 2.6816x; 1.0548x over previous
//
#include <hip/hip_runtime.h>
#include <math.h>

#define NB   8
#define SEQ  1024
#define DIM  256

static constexpr float LN_EPS_C = 1e-5f;

typedef __bf16 bfx8 __attribute__((ext_vector_type(8)));
typedef __bf16 bfx4 __attribute__((ext_vector_type(4)));
typedef float  f32v4 __attribute__((ext_vector_type(4)));

// async global->LDS, 16B/lane; LDS dest = wave-uniform base + lane*16
__device__ inline void gll16(const void* g, void* l) {
    __builtin_amdgcn_global_load_lds(
        (const __attribute__((address_space(1))) void*)g,
        (__attribute__((address_space(3))) void*)l, 16, 0, 0);
}

// ---------------------------------------------------------------------------
// prep: blocks 0..255 transpose-cast L -> Lt[s][k]; blocks 256..319 cast P->bf16
// ---------------------------------------------------------------------------
__global__ void __launch_bounds__(256)
k_prep(const float* __restrict__ L, const float* __restrict__ P,
       __bf16* __restrict__ Lt, __bf16* __restrict__ Pb)
{
    const int bx = blockIdx.x;
    if (bx < 256) {
        __shared__ __bf16 ts[64][72];
        const int r0 = (bx & 15) * 64;
        const int c0 = (bx >> 4) * 64;
        const int t = threadIdx.x;
        const int r = t >> 2, cb = (t & 3) * 16;
        const float* sp = L + (size_t)(r0 + r) * SEQ + c0 + cb;
        #pragma unroll
        for (int u = 0; u < 4; ++u) {
            const float4 v = *reinterpret_cast<const float4*>(sp + u * 4);
            ts[r][cb + u*4 + 0] = (__bf16)v.x;
            ts[r][cb + u*4 + 1] = (__bf16)v.y;
            ts[r][cb + u*4 + 2] = (__bf16)v.z;
            ts[r][cb + u*4 + 3] = (__bf16)v.w;
        }
        __syncthreads();
        const int dl = t >> 2, kb = (t & 3) * 16;
        bfx8 o0, o1;
        #pragma unroll
        for (int e = 0; e < 8; ++e) { o0[e] = ts[kb + e][dl]; o1[e] = ts[kb + 8 + e][dl]; }
        __bf16* dp = Lt + (size_t)(c0 + dl) * SEQ + r0 + kb;
        *reinterpret_cast<bfx8*>(dp)     = o0;
        *reinterpret_cast<bfx8*>(dp + 8) = o1;
    } else {
        const int idx = ((bx - 256) * 256 + threadIdx.x) * 4;
        const float4 v = *reinterpret_cast<const float4*>(P + idx);
        bfx4 o;
        o[0] = (__bf16)v.x; o[1] = (__bf16)v.y; o[2] = (__bf16)v.z; o[3] = (__bf16)v.w;
        *reinterpret_cast<bfx4*>(Pb + idx) = o;
    }
}

// ---------------------------------------------------------------------------
// V[b][k][d] -> Vt[b][d][k]  (bf16, 64x64 tiles)
// ---------------------------------------------------------------------------
__global__ void __launch_bounds__(256)
k_transV(const __bf16* __restrict__ src, __bf16* __restrict__ dst)
{
    __shared__ __bf16 ts[64][72];
    const long z = blockIdx.z;
    const int r0 = blockIdx.x * 64;   // k
    const int c0 = blockIdx.y * 64;   // d
    const int t  = threadIdx.x;
    const int r  = t >> 2, cb = (t & 3) * 16;

    const __bf16* sp = src + z * (SEQ * DIM) + (size_t)(r0 + r) * DIM + c0 + cb;
    #pragma unroll
    for (int u = 0; u < 2; ++u) {
        const bfx8 v = *reinterpret_cast<const bfx8*>(sp + u * 8);
        #pragma unroll
        for (int e = 0; e < 8; ++e) ts[r][cb + u*8 + e] = v[e];
    }
    __syncthreads();

    const int dl = t >> 2, kb = (t & 3) * 16;
    bfx8 o0, o1;
    #pragma unroll
    for (int e = 0; e < 8; ++e) { o0[e] = ts[kb + e][dl]; o1[e] = ts[kb + 8 + e][dl]; }
    __bf16* dp = dst + z * (SEQ * DIM) + (size_t)(c0 + dl) * SEQ + r0 + kb;
    *reinterpret_cast<bfx8*>(dp)     = o0;
    *reinterpret_cast<bfx8*>(dp + 8) = o1;
}

// ---------------------------------------------------------------------------
// GEMM1 (fp32 inputs, in-register cvt): Zl[m][n] = sum_k x[m][k]*M[n][k], bf16 out
// Tile 64x64x64, double-buffered, 1 barrier/K-step, 2x2 wave tiling.
// fp32 LDS rows = 16 chunks of 16B; chunk c stored at c^(row&15).
// ---------------------------------------------------------------------------
__global__ void __launch_bounds__(256)
k_gemm1(const float* __restrict__ X, const float* __restrict__ Mw,
        __bf16* __restrict__ Zl)
{
    __shared__ float As[2][64 * 64];
    __shared__ float Bs[2][64 * 64];
    const int m0 = blockIdx.x * 64;
    const int n0 = blockIdx.y * 64;
    const int t = threadIdx.x, l = t & 63, w = t >> 6;
    const int wm = w >> 1, wn = w & 1;

    f32v4 acc[2][2] = {};

    auto stage = [&](int buf, int k0) {
        #pragma unroll
        for (int q = 0; q < 4; ++q) {
            const int p   = 4 * w + q;               // 1KB page (4 rows)
            const int row = p * 4 + (l >> 4);
            const int cs  = (l & 15) ^ (row & 15);   // pre-swizzled source chunk
            gll16(X  + (size_t)(m0 + row) * 256 + k0 + cs * 4, &As[buf][p * 256]);
            gll16(Mw + (size_t)(n0 + row) * 256 + k0 + cs * 4, &Bs[buf][p * 256]);
        }
    };

    stage(0, 0);
    int cur = 0;
    #pragma unroll
    for (int ts_ = 0; ts_ < 4; ++ts_) {
        __syncthreads();                      // drain stage(ts_)
        if (ts_ < 3) stage(cur ^ 1, (ts_ + 1) * 64);
        #pragma unroll
        for (int ks = 0; ks < 2; ++ks) {
            const int c0 = ks * 8 + (l >> 4) * 2;
            const int r15 = l & 15;
            bfx8 af[2], bfr[2];
            #pragma unroll
            for (int i = 0; i < 2; ++i) {
                const int Ra = 32 * wm + 16 * i + (l & 15);
                const float4 f0 = *reinterpret_cast<const float4*>(&As[cur][Ra * 64 + (( c0      ^ r15) << 2)]);
                const float4 f1 = *reinterpret_cast<const float4*>(&As[cur][Ra * 64 + (((c0 + 1) ^ r15) << 2)]);
                af[i][0]=(__bf16)f0.x; af[i][1]=(__bf16)f0.y; af[i][2]=(__bf16)f0.z; af[i][3]=(__bf16)f0.w;
                af[i][4]=(__bf16)f1.x; af[i][5]=(__bf16)f1.y; af[i][6]=(__bf16)f1.z; af[i][7]=(__bf16)f1.w;
                const int Rb = 32 * wn + 16 * i + (l & 15);
                const float4 g0 = *reinterpret_cast<const float4*>(&Bs[cur][Rb * 64 + (( c0      ^ r15) << 2)]);
                const float4 g1 = *reinterpret_cast<const float4*>(&Bs[cur][Rb * 64 + (((c0 + 1) ^ r15) << 2)]);
                bfr[i][0]=(__bf16)g0.x; bfr[i][1]=(__bf16)g0.y; bfr[i][2]=(__bf16)g0.z; bfr[i][3]=(__bf16)g0.w;
                bfr[i][4]=(__bf16)g1.x; bfr[i][5]=(__bf16)g1.y; bfr[i][6]=(__bf16)g1.z; bfr[i][7]=(__bf16)g1.w;
            }
            #pragma unroll
            for (int i = 0; i < 2; ++i)
                #pragma unroll
                for (int j = 0; j < 2; ++j)
                    acc[i][j] = __builtin_amdgcn_mfma_f32_16x16x32_bf16(af[i], bfr[j], acc[i][j], 0, 0, 0);
        }
        cur ^= 1;
    }

    const int col = l & 15;
    #pragma unroll
    for (int i = 0; i < 2; ++i)
        #pragma unroll
        for (int j = 0; j < 2; ++j)
            #pragma unroll
            for (int r = 0; r < 4; ++r)
                Zl[(size_t)(m0 + 32*wm + 16*i + 4*(l >> 4) + r) * 256 + n0 + 32*wn + 16*j + col]
                    = (__bf16)acc[i][j][r];
}

// ---------------------------------------------------------------------------
// GEMM2 (bf16): out[b][s][d] = sum_k Lt[s][k] * Vt[b][d][k]  (fp32 out)
// Tile 64x64x64, double-buffered, 1 barrier/K-step, 2x2 wave tiling.
// ---------------------------------------------------------------------------
__global__ void __launch_bounds__(256)
k_gemm2(const __bf16* __restrict__ A, const __bf16* __restrict__ Bt,
        float* __restrict__ C)
{
    __shared__ __bf16 As[2][64 * 64];
    __shared__ __bf16 Bs[2][64 * 64];
    const int m0 = blockIdx.x * 64;   // s
    const int n0 = blockIdx.y * 64;   // d
    const long zb = blockIdx.z;
    const int t = threadIdx.x, l = t & 63, w = t >> 6;
    const int wm = w >> 1, wn = w & 1;
    const __bf16* Bz = Bt + zb * (SEQ * DIM);

    f32v4 acc[2][2] = {};

    auto stage = [&](int buf, int k0) {
        #pragma unroll
        for (int q = 0; q < 2; ++q) {
            const int p  = 2 * w + q;
            const int rr = p * 8 + (l >> 3);
            const int sc = (l & 7) ^ (l >> 3);
            gll16(A  + (size_t)(m0 + rr) * SEQ + k0 + sc * 8, &As[buf][p * 512]);
            gll16(Bz + (size_t)(n0 + rr) * SEQ + k0 + sc * 8, &Bs[buf][p * 512]);
        }
    };

    stage(0, 0);
    int cur = 0;
    for (int ts_ = 0; ts_ < 16; ++ts_) {
        __syncthreads();                      // drain stage(ts_)
        if (ts_ < 15) stage(cur ^ 1, (ts_ + 1) * 64);
        #pragma unroll
        for (int ks = 0; ks < 2; ++ks) {
            const int lch = ks * 4 + (l >> 4);
            const int ph  = ((lch ^ (l & 7)) << 3);
            bfx8 af[2], bfr[2];
            #pragma unroll
            for (int i = 0; i < 2; ++i) {
                af[i]  = *reinterpret_cast<const bfx8*>(&As[cur][(32*wm + 16*i + (l & 15)) * 64 + ph]);
                bfr[i] = *reinterpret_cast<const bfx8*>(&Bs[cur][(32*wn + 16*i + (l & 15)) * 64 + ph]);
            }
            #pragma unroll
            for (int i = 0; i < 2; ++i)
                #pragma unroll
                for (int j = 0; j < 2; ++j)
                    acc[i][j] = __builtin_amdgcn_mfma_f32_16x16x32_bf16(af[i], bfr[j], acc[i][j], 0, 0, 0);
        }
        cur ^= 1;
    }

    const int col = l & 15;
    #pragma unroll
    for (int i = 0; i < 2; ++i)
        #pragma unroll
        for (int j = 0; j < 2; ++j)
            #pragma unroll
            for (int r = 0; r < 4; ++r)
                C[zb * (size_t)(SEQ * DIM)
                  + (size_t)(m0 + 32*wm + 16*i + 4*(l >> 4) + r) * 256
                  + n0 + 32*wn + 16*j + col] = acc[i][j][r];
}

// ---------------------------------------------------------------------------
// Gate via MFMA: block = one k. LN rows in LDS, W synthesized per-lane in regs.
// ---------------------------------------------------------------------------
__global__ void __launch_bounds__(256, 4)
k_gateM(const __bf16* __restrict__ Zl, const __bf16* __restrict__ Pb,
        const float* __restrict__ gamma, const float* __restrict__ beta,
        __bf16* __restrict__ V)
{
    __shared__ __bf16 zraw[8 * 256];
    __shared__ __bf16 znorm[16 * 256];
    __shared__ float mu_s[8], rs_s[8];

    const int k = blockIdx.x;
    const int t = threadIdx.x;
    const int l = t & 63, w = t >> 6;

    const int m  = t >> 5;
    const int ch = t & 31;
    const bfx8 zv = *reinterpret_cast<const bfx8*>(Zl + ((size_t)(m * SEQ + k)) * DIM + ch * 8);
    *reinterpret_cast<bfx8*>(&zraw[m * 256 + ((ch ^ m) << 3)]) = zv;

    bfx8 zz;
    #pragma unroll
    for (int e = 0; e < 8; ++e) zz[e] = (__bf16)0.f;
    *reinterpret_cast<bfx8*>(&znorm[(8 + m) * 256 + ((ch ^ m) << 3)]) = zz;

    float s1 = 0.f, s2 = 0.f;
    #pragma unroll
    for (int e = 0; e < 8; ++e) { const float v = (float)zv[e]; s1 += v; s2 += v * v; }
    #pragma unroll
    for (int q = 16; q >= 1; q >>= 1) { s1 += __shfl_xor(s1, q); s2 += __shfl_xor(s2, q); }
    if (ch == 0) {
        const float mu  = s1 * (1.f / DIM);
        const float var = s2 * (1.f / DIM) - mu * mu;
        mu_s[m] = mu;
        rs_s[m] = rsqrtf(var + LN_EPS_C);
    }
    __syncthreads();

    {
        const float mu = mu_s[m], rs = rs_s[m];
        const float4 g0 = *reinterpret_cast<const float4*>(gamma + ch * 8);
        const float4 g1 = *reinterpret_cast<const float4*>(gamma + ch * 8 + 4);
        const float4 b0 = *reinterpret_cast<const float4*>(beta  + ch * 8);
        const float4 b1 = *reinterpret_cast<const float4*>(beta  + ch * 8 + 4);
        const float gv[8] = {g0.x, g0.y, g0.z, g0.w, g1.x, g1.y, g1.z, g1.w};
        const float bv[8] = {b0.x, b0.y, b0.z, b0.w, b1.x, b1.y, b1.z, b1.w};
        bfx8 nv;
        #pragma unroll
        for (int e = 0; e < 8; ++e)
            nv[e] = (__bf16)(((float)zv[e] - mu) * rs * gv[e] + bv[e]);
        *reinterpret_cast<bfx8*>(&znorm[m * 256 + ((ch ^ m) << 3)]) = nv;
    }
    __syncthreads();

    const int mm = l & 15;
    bfx8 af[8];
    #pragma unroll
    for (int ks = 0; ks < 8; ++ks) {
        const int cc = ks * 4 + (l >> 4);
        af[ks] = *reinterpret_cast<const bfx8*>(&znorm[mm * 256 + ((cc ^ (mm & 7)) << 3)]);
    }

    const float kf = (float)k;
    const int n0w = w * 64;
    f32v4 acc[4] = {};
    #pragma unroll
    for (int c = 0; c < 4; ++c) {
        const int i = n0w + 16 * c + (l & 15);
        const __bf16* Prow = Pb + (size_t)i * DIM;
        #pragma unroll
        for (int ks = 0; ks < 8; ++ks) {
            const int jb = ks * 32 + (l >> 4) * 8;
            const bfx8 pv = *reinterpret_cast<const bfx8*>(Prow + jb);
            const float pbase = (float)(i * DIM + jb + 2);
            bfx8 wf;
            #pragma unroll
            for (int e = 0; e < 8; ++e) {
                float r = kf * __builtin_amdgcn_rcpf(pbase + (float)e);
                r -= floorf(r);
                wf[e] = (__bf16)(__builtin_amdgcn_cosf(r) * (float)pv[e]);
            }
            acc[c] = __builtin_amdgcn_mfma_f32_16x16x32_bf16(af[ks], wf, acc[c], 0, 0, 0);
        }
    }

    const int g = l >> 4;
    if (g < 2) {
        const int col = l & 15;
        #pragma unroll
        for (int c = 0; c < 4; ++c) {
            const int i = n0w + 16 * c + col;
            #pragma unroll
            for (int r = 0; r < 4; ++r) {
                const int b = 4 * g + r;
                const float resid = (float)zraw[b * 256 + (((i >> 3) ^ b) << 3) + (i & 7)];
                V[((size_t)(b * SEQ + k)) * DIM + i] = (__bf16)(acc[c][r] + resid);
            }
        }
    }
}

// ---------------------------------------------------------------------------
extern "C" void kernel_launch(void* const* d_in, const int* in_sizes, int n_in,
                              void* d_out, int out_size, void* d_ws, size_t ws_size,
                              hipStream_t stream)
{
    const float* x     = (const float*)d_in[0];
    const float* M     = (const float*)d_in[1];
    const float* P     = (const float*)d_in[2];
    const float* L     = (const float*)d_in[3];
    const float* gamma = (const float*)d_in[4];
    const float* beta  = (const float*)d_in[5];
    float* out = (float*)d_out;

    char* ws = (char*)d_ws;
    __bf16* Pb = (__bf16*)(ws);                                 // 128 KB [256][256]
    __bf16* Lt = (__bf16*)(ws + (128u << 10));                  // 2 MB   [1024 s][1024 k]
    __bf16* Zl = (__bf16*)(ws + (2u << 20) + (128u << 10));     // 4 MB   [8192][256]
    __bf16* V  = (__bf16*)(ws + (6u << 20) + (128u << 10));     // 4 MB   [b][k][d]
    __bf16* Vt = (__bf16*)(ws + (10u << 20) + (128u << 10));    // 4 MB   [b][d][k]

    // prep: Lt transpose (256 blocks) + P cast (64 blocks)
    hipLaunchKernelGGL(k_prep, dim3(320), dim3(256), 0, stream, L, P, Lt, Pb);

    // GEMM1 (fp32 in, bf16 out): Zl = x @ M^T
    hipLaunchKernelGGL(k_gemm1, dim3(128, 4), dim3(256), 0, stream, x, M, Zl);

    // gate: LN + cos-gated MFMA + residual -> V bf16
    hipLaunchKernelGGL(k_gateM, dim3(SEQ), dim3(256), 0, stream,
                       Zl, Pb, gamma, beta, V);

    // V -> Vt
    hipLaunchKernelGGL(k_transV, dim3(16, 4, 8), dim3(256), 0, stream, V, Vt);

    // GEMM2: out = Lt @ Vt^T per batch
    hipLaunchKernelGGL(k_gemm2, dim3(16, 4, 8), dim3(256), 0, stream, Lt, Vt, out);
}

// Round 7
// 56.544 us; speedup vs baseline: 2.9395x; 1.0962x over previous
//
#include <hip/hip_runtime.h>
#include <math.h>

#define NB   8
#define SEQ  1024
#define DIM  256

static constexpr float LN_EPS_C = 1e-5f;

typedef __bf16 bfx8 __attribute__((ext_vector_type(8)));
typedef __bf16 bfx4 __attribute__((ext_vector_type(4)));
typedef float  f32v4 __attribute__((ext_vector_type(4)));

// async global->LDS, 16B/lane; LDS dest = wave-uniform base + lane*16
__device__ inline void gll16(const void* g, void* l) {
    __builtin_amdgcn_global_load_lds(
        (const __attribute__((address_space(1))) void*)g,
        (__attribute__((address_space(3))) void*)l, 16, 0, 0);
}

// ---------------------------------------------------------------------------
// K1: fused prep + GEMM1.
//  blocks [0,512):   Zl[m][n] = sum_k x[m][k]*M[n][k]  (fp32 in, bf16 out)
//  blocks [512,768): transpose-cast L -> Lt[s][k]
//  blocks [768,832): cast P -> bf16
// ---------------------------------------------------------------------------
__global__ void __launch_bounds__(256)
k_pg1(const float* __restrict__ X, const float* __restrict__ Mw,
      const float* __restrict__ L, const float* __restrict__ P,
      __bf16* __restrict__ Zl, __bf16* __restrict__ Lt, __bf16* __restrict__ Pb)
{
    __shared__ __align__(16) char smraw[65536];
    const int bx = blockIdx.x;
    const int t  = threadIdx.x;

    if (bx >= 768) {                 // ---- P cast ----
        const int idx = ((bx - 768) * 256 + t) * 4;
        const float4 v = *reinterpret_cast<const float4*>(P + idx);
        bfx4 o;
        o[0] = (__bf16)v.x; o[1] = (__bf16)v.y; o[2] = (__bf16)v.z; o[3] = (__bf16)v.w;
        *reinterpret_cast<bfx4*>(Pb + idx) = o;
        return;
    }
    if (bx >= 512) {                 // ---- L transpose-cast ----
        auto ts = reinterpret_cast<__bf16(*)[72]>(smraw);
        const int b2 = bx - 512;
        const int r0 = (b2 & 15) * 64;
        const int c0 = (b2 >> 4) * 64;
        const int r = t >> 2, cb = (t & 3) * 16;
        const float* sp = L + (size_t)(r0 + r) * SEQ + c0 + cb;
        #pragma unroll
        for (int u = 0; u < 4; ++u) {
            const float4 v = *reinterpret_cast<const float4*>(sp + u * 4);
            ts[r][cb + u*4 + 0] = (__bf16)v.x;
            ts[r][cb + u*4 + 1] = (__bf16)v.y;
            ts[r][cb + u*4 + 2] = (__bf16)v.z;
            ts[r][cb + u*4 + 3] = (__bf16)v.w;
        }
        __syncthreads();
        const int dl = t >> 2, kb = (t & 3) * 16;
        bfx8 o0, o1;
        #pragma unroll
        for (int e = 0; e < 8; ++e) { o0[e] = ts[kb + e][dl]; o1[e] = ts[kb + 8 + e][dl]; }
        __bf16* dp = Lt + (size_t)(c0 + dl) * SEQ + r0 + kb;
        *reinterpret_cast<bfx8*>(dp)     = o0;
        *reinterpret_cast<bfx8*>(dp + 8) = o1;
        return;
    }

    // ---- GEMM1: tile 64x64x64, dbuf, 2x2 wave tiling, fp32 LDS + in-reg cvt ----
    float* AsP = reinterpret_cast<float*>(smraw);            // [2][4096]
    float* BsP = reinterpret_cast<float*>(smraw + 32768);    // [2][4096]
    const int m0 = (bx & 127) * 64;
    const int n0 = (bx >> 7) * 64;
    const int l = t & 63, w = t >> 6;
    const int wm = w >> 1, wn = w & 1;

    f32v4 acc[2][2] = {};

    auto stage = [&](int buf, int k0) {
        #pragma unroll
        for (int q = 0; q < 4; ++q) {
            const int p   = 4 * w + q;               // 1KB page (4 rows)
            const int row = p * 4 + (l >> 4);
            const int cs  = (l & 15) ^ (row & 15);   // pre-swizzled source chunk
            gll16(X  + (size_t)(m0 + row) * 256 + k0 + cs * 4, &AsP[buf*4096 + p*256]);
            gll16(Mw + (size_t)(n0 + row) * 256 + k0 + cs * 4, &BsP[buf*4096 + p*256]);
        }
    };

    stage(0, 0);
    int cur = 0;
    #pragma unroll
    for (int ts_ = 0; ts_ < 4; ++ts_) {
        __syncthreads();
        if (ts_ < 3) stage(cur ^ 1, (ts_ + 1) * 64);
        #pragma unroll
        for (int ks = 0; ks < 2; ++ks) {
            const int c0 = ks * 8 + (l >> 4) * 2;
            const int r15 = l & 15;
            bfx8 af[2], bfr[2];
            #pragma unroll
            for (int i = 0; i < 2; ++i) {
                const int Ra = 32 * wm + 16 * i + (l & 15);
                const float4 f0 = *reinterpret_cast<const float4*>(&AsP[cur*4096 + Ra*64 + (( c0      ^ r15) << 2)]);
                const float4 f1 = *reinterpret_cast<const float4*>(&AsP[cur*4096 + Ra*64 + (((c0 + 1) ^ r15) << 2)]);
                af[i][0]=(__bf16)f0.x; af[i][1]=(__bf16)f0.y; af[i][2]=(__bf16)f0.z; af[i][3]=(__bf16)f0.w;
                af[i][4]=(__bf16)f1.x; af[i][5]=(__bf16)f1.y; af[i][6]=(__bf16)f1.z; af[i][7]=(__bf16)f1.w;
                const int Rb = 32 * wn + 16 * i + (l & 15);
                const float4 g0 = *reinterpret_cast<const float4*>(&BsP[cur*4096 + Rb*64 + (( c0      ^ r15) << 2)]);
                const float4 g1 = *reinterpret_cast<const float4*>(&BsP[cur*4096 + Rb*64 + (((c0 + 1) ^ r15) << 2)]);
                bfr[i][0]=(__bf16)g0.x; bfr[i][1]=(__bf16)g0.y; bfr[i][2]=(__bf16)g0.z; bfr[i][3]=(__bf16)g0.w;
                bfr[i][4]=(__bf16)g1.x; bfr[i][5]=(__bf16)g1.y; bfr[i][6]=(__bf16)g1.z; bfr[i][7]=(__bf16)g1.w;
            }
            #pragma unroll
            for (int i = 0; i < 2; ++i)
                #pragma unroll
                for (int j = 0; j < 2; ++j)
                    acc[i][j] = __builtin_amdgcn_mfma_f32_16x16x32_bf16(af[i], bfr[j], acc[i][j], 0, 0, 0);
        }
        cur ^= 1;
    }

    const int col = l & 15;
    #pragma unroll
    for (int i = 0; i < 2; ++i)
        #pragma unroll
        for (int j = 0; j < 2; ++j)
            #pragma unroll
            for (int r = 0; r < 4; ++r)
                Zl[(size_t)(m0 + 32*wm + 16*i + 4*(l >> 4) + r) * 256 + n0 + 32*wn + 16*j + col]
                    = (__bf16)acc[i][j][r];
}

// ---------------------------------------------------------------------------
// K2: gate via MFMA. block = one k. LN rows in LDS, W synthesized in regs.
// ---------------------------------------------------------------------------
__global__ void __launch_bounds__(256, 4)
k_gateM(const __bf16* __restrict__ Zl, const __bf16* __restrict__ Pb,
        const float* __restrict__ gamma, const float* __restrict__ beta,
        __bf16* __restrict__ V)
{
    __shared__ __bf16 zraw[8 * 256];
    __shared__ __bf16 znorm[16 * 256];
    __shared__ float mu_s[8], rs_s[8];

    const int k = blockIdx.x;
    const int t = threadIdx.x;
    const int l = t & 63, w = t >> 6;

    const int m  = t >> 5;
    const int ch = t & 31;
    const bfx8 zv = *reinterpret_cast<const bfx8*>(Zl + ((size_t)(m * SEQ + k)) * DIM + ch * 8);
    *reinterpret_cast<bfx8*>(&zraw[m * 256 + ((ch ^ m) << 3)]) = zv;

    bfx8 zz;
    #pragma unroll
    for (int e = 0; e < 8; ++e) zz[e] = (__bf16)0.f;
    *reinterpret_cast<bfx8*>(&znorm[(8 + m) * 256 + ((ch ^ m) << 3)]) = zz;

    float s1 = 0.f, s2 = 0.f;
    #pragma unroll
    for (int e = 0; e < 8; ++e) { const float v = (float)zv[e]; s1 += v; s2 += v * v; }
    #pragma unroll
    for (int q = 16; q >= 1; q >>= 1) { s1 += __shfl_xor(s1, q); s2 += __shfl_xor(s2, q); }
    if (ch == 0) {
        const float mu  = s1 * (1.f / DIM);
        const float var = s2 * (1.f / DIM) - mu * mu;
        mu_s[m] = mu;
        rs_s[m] = rsqrtf(var + LN_EPS_C);
    }
    __syncthreads();

    {
        const float mu = mu_s[m], rs = rs_s[m];
        const float4 g0 = *reinterpret_cast<const float4*>(gamma + ch * 8);
        const float4 g1 = *reinterpret_cast<const float4*>(gamma + ch * 8 + 4);
        const float4 b0 = *reinterpret_cast<const float4*>(beta  + ch * 8);
        const float4 b1 = *reinterpret_cast<const float4*>(beta  + ch * 8 + 4);
        const float gv[8] = {g0.x, g0.y, g0.z, g0.w, g1.x, g1.y, g1.z, g1.w};
        const float bv[8] = {b0.x, b0.y, b0.z, b0.w, b1.x, b1.y, b1.z, b1.w};
        bfx8 nv;
        #pragma unroll
        for (int e = 0; e < 8; ++e)
            nv[e] = (__bf16)(((float)zv[e] - mu) * rs * gv[e] + bv[e]);
        *reinterpret_cast<bfx8*>(&znorm[m * 256 + ((ch ^ m) << 3)]) = nv;
    }
    __syncthreads();

    const int mm = l & 15;
    bfx8 af[8];
    #pragma unroll
    for (int ks = 0; ks < 8; ++ks) {
        const int cc = ks * 4 + (l >> 4);
        af[ks] = *reinterpret_cast<const bfx8*>(&znorm[mm * 256 + ((cc ^ (mm & 7)) << 3)]);
    }

    const float kf = (float)k;
    const int n0w = w * 64;
    f32v4 acc[4] = {};
    #pragma unroll
    for (int c = 0; c < 4; ++c) {
        const int i = n0w + 16 * c + (l & 15);
        const __bf16* Prow = Pb + (size_t)i * DIM;
        #pragma unroll
        for (int ks = 0; ks < 8; ++ks) {
            const int jb = ks * 32 + (l >> 4) * 8;
            const bfx8 pv = *reinterpret_cast<const bfx8*>(Prow + jb);
            const float pbase = (float)(i * DIM + jb + 2);
            bfx8 wf;
            #pragma unroll
            for (int e = 0; e < 8; ++e) {
                float r = kf * __builtin_amdgcn_rcpf(pbase + (float)e);
                r = __builtin_amdgcn_fractf(r);       // revolutions in [0,1)
                wf[e] = (__bf16)(__builtin_amdgcn_cosf(r) * (float)pv[e]);
            }
            acc[c] = __builtin_amdgcn_mfma_f32_16x16x32_bf16(af[ks], wf, acc[c], 0, 0, 0);
        }
    }

    const int g = l >> 4;
    if (g < 2) {
        const int col = l & 15;
        #pragma unroll
        for (int c = 0; c < 4; ++c) {
            const int i = n0w + 16 * c + col;
            #pragma unroll
            for (int r = 0; r < 4; ++r) {
                const int b = 4 * g + r;
                const float resid = (float)zraw[b * 256 + (((i >> 3) ^ b) << 3) + (i & 7)];
                V[((size_t)(b * SEQ + k)) * DIM + i] = (__bf16)(acc[c][r] + resid);
            }
        }
    }
}

// ---------------------------------------------------------------------------
// K3: V[b][k][d] -> Vt[b][d][k]  (bf16, 64x64 tiles)  [proven round-5 path]
// ---------------------------------------------------------------------------
__global__ void __launch_bounds__(256)
k_transV(const __bf16* __restrict__ src, __bf16* __restrict__ dst)
{
    __shared__ __bf16 ts[64][72];
    const long z = blockIdx.z;
    const int r0 = blockIdx.x * 64;   // k
    const int c0 = blockIdx.y * 64;   // d
    const int t  = threadIdx.x;
    const int r  = t >> 2, cb = (t & 3) * 16;

    const __bf16* sp = src + z * (SEQ * DIM) + (size_t)(r0 + r) * DIM + c0 + cb;
    #pragma unroll
    for (int u = 0; u < 2; ++u) {
        const bfx8 v = *reinterpret_cast<const bfx8*>(sp + u * 8);
        #pragma unroll
        for (int e = 0; e < 8; ++e) ts[r][cb + u*8 + e] = v[e];
    }
    __syncthreads();

    const int dl = t >> 2, kb = (t & 3) * 16;
    bfx8 o0, o1;
    #pragma unroll
    for (int e = 0; e < 8; ++e) { o0[e] = ts[kb + e][dl]; o1[e] = ts[kb + 8 + e][dl]; }
    __bf16* dp = dst + z * (SEQ * DIM) + (size_t)(c0 + dl) * SEQ + r0 + kb;
    *reinterpret_cast<bfx8*>(dp)     = o0;
    *reinterpret_cast<bfx8*>(dp + 8) = o1;
}

// ---------------------------------------------------------------------------
// K4: out[b][s][d] = sum_k Lt[s][k] * Vt[b][d][k]  (fp32 out)
// Tile 64x64x64, double-buffered, 1 barrier/K-step, 2x2 wave tiling.
// [proven round-5 path]
// ---------------------------------------------------------------------------
__global__ void __launch_bounds__(256)
k_gemm2(const __bf16* __restrict__ A, const __bf16* __restrict__ Bt,
        float* __restrict__ C)
{
    __shared__ __bf16 As[2][64 * 64];
    __shared__ __bf16 Bs[2][64 * 64];
    const int m0 = blockIdx.x * 64;   // s
    const int n0 = blockIdx.y * 64;   // d
    const long zb = blockIdx.z;
    const int t = threadIdx.x, l = t & 63, w = t >> 6;
    const int wm = w >> 1, wn = w & 1;
    const __bf16* Bz = Bt + zb * (SEQ * DIM);

    f32v4 acc[2][2] = {};

    auto stage = [&](int buf, int k0) {
        #pragma unroll
        for (int q = 0; q < 2; ++q) {
            const int p  = 2 * w + q;
            const int rr = p * 8 + (l >> 3);
            const int sc = (l & 7) ^ (l >> 3);
            gll16(A  + (size_t)(m0 + rr) * SEQ + k0 + sc * 8, &As[buf][p * 512]);
            gll16(Bz + (size_t)(n0 + rr) * SEQ + k0 + sc * 8, &Bs[buf][p * 512]);
        }
    };

    stage(0, 0);
    int cur = 0;
    for (int ts_ = 0; ts_ < 16; ++ts_) {
        __syncthreads();                      // drain stage(ts_)
        if (ts_ < 15) stage(cur ^ 1, (ts_ + 1) * 64);
        #pragma unroll
        for (int ks = 0; ks < 2; ++ks) {
            const int lch = ks * 4 + (l >> 4);
            const int ph  = ((lch ^ (l & 7)) << 3);
            bfx8 af[2], bfr[2];
            #pragma unroll
            for (int i = 0; i < 2; ++i) {
                af[i]  = *reinterpret_cast<const bfx8*>(&As[cur][(32*wm + 16*i + (l & 15)) * 64 + ph]);
                bfr[i] = *reinterpret_cast<const bfx8*>(&Bs[cur][(32*wn + 16*i + (l & 15)) * 64 + ph]);
            }
            #pragma unroll
            for (int i = 0; i < 2; ++i)
                #pragma unroll
                for (int j = 0; j < 2; ++j)
                    acc[i][j] = __builtin_amdgcn_mfma_f32_16x16x32_bf16(af[i], bfr[j], acc[i][j], 0, 0, 0);
        }
        cur ^= 1;
    }

    const int col = l & 15;
    #pragma unroll
    for (int i = 0; i < 2; ++i)
        #pragma unroll
        for (int j = 0; j < 2; ++j)
            #pragma unroll
            for (int r = 0; r < 4; ++r)
                C[zb * (size_t)(SEQ * DIM)
                  + (size_t)(m0 + 32*wm + 16*i + 4*(l >> 4) + r) * 256
                  + n0 + 32*wn + 16*j + col] = acc[i][j][r];
}

// ---------------------------------------------------------------------------
extern "C" void kernel_launch(void* const* d_in, const int* in_sizes, int n_in,
                              void* d_out, int out_size, void* d_ws, size_t ws_size,
                              hipStream_t stream)
{
    const float* x     = (const float*)d_in[0];
    const float* M     = (const float*)d_in[1];
    const float* P     = (const float*)d_in[2];
    const float* L     = (const float*)d_in[3];
    const float* gamma = (const float*)d_in[4];
    const float* beta  = (const float*)d_in[5];
    float* out = (float*)d_out;

    char* ws = (char*)d_ws;
    __bf16* Pb = (__bf16*)(ws);                              // 128 KB [256][256]
    __bf16* Lt = (__bf16*)(ws + (128u << 10));               // 2 MB   [1024 s][1024 k]
    __bf16* Zl = (__bf16*)(ws + (2u << 20) + (128u << 10));  // 4 MB   [8192][256]
    __bf16* V  = (__bf16*)(ws + (6u << 20) + (128u << 10));  // 4 MB   [b][k][d]
    __bf16* Vt = (__bf16*)(ws + (10u << 20) + (128u << 10)); // 4 MB   [b][d][k]

    // K1: prep (L-transpose + P-cast) + GEMM1
    hipLaunchKernelGGL(k_pg1, dim3(832), dim3(256), 0, stream,
                       x, M, L, P, Zl, Lt, Pb);

    // K2: LN + cos-gated MFMA + residual -> V bf16
    hipLaunchKernelGGL(k_gateM, dim3(SEQ), dim3(256), 0, stream,
                       Zl, Pb, gamma, beta, V);

    // K3: V -> Vt
    hipLaunchKernelGGL(k_transV, dim3(16, 4, 8), dim3(256), 0, stream, V, Vt);

    // K4: out = Lt @ Vt^T per batch
    hipLaunchKernelGGL(k_gemm2, dim3(16, 4, 8), dim3(256), 0, stream, Lt, Vt, out);
}

// Round 8
// 53.420 us; speedup vs baseline: 3.1114x; 1.0585x over previous
//
#include <hip/hip_runtime.h>
#include <math.h>

#define NB   8
#define SEQ  1024
#define DIM  256

static constexpr float LN_EPS_C = 1e-5f;

typedef __bf16 bfx8 __attribute__((ext_vector_type(8)));
typedef __bf16 bfx4 __attribute__((ext_vector_type(4)));
typedef float  f32v4 __attribute__((ext_vector_type(4)));

// async global->LDS, 16B/lane; LDS dest = wave-uniform base + lane*16
__device__ inline void gll16(const void* g, void* l) {
    __builtin_amdgcn_global_load_lds(
        (const __attribute__((address_space(1))) void*)g,
        (__attribute__((address_space(3))) void*)l, 16, 0, 0);
}

// ---------------------------------------------------------------------------
// K1: fused prep + GEMM1.
//  blocks [0,512):   Zl[m][n] = sum_k x[m][k]*M[n][k]  (fp32 in, bf16 out)
//  blocks [512,768): transpose-cast L -> Lt[s][k]
//  blocks [768,832): cast P -> bf16
// ---------------------------------------------------------------------------
__global__ void __launch_bounds__(256)
k_pg1(const float* __restrict__ X, const float* __restrict__ Mw,
      const float* __restrict__ L, const float* __restrict__ P,
      __bf16* __restrict__ Zl, __bf16* __restrict__ Lt, __bf16* __restrict__ Pb)
{
    __shared__ __align__(16) char smraw[65536];
    const int bx = blockIdx.x;
    const int t  = threadIdx.x;

    if (bx >= 768) {                 // ---- P cast ----
        const int idx = ((bx - 768) * 256 + t) * 4;
        const float4 v = *reinterpret_cast<const float4*>(P + idx);
        bfx4 o;
        o[0] = (__bf16)v.x; o[1] = (__bf16)v.y; o[2] = (__bf16)v.z; o[3] = (__bf16)v.w;
        *reinterpret_cast<bfx4*>(Pb + idx) = o;
        return;
    }
    if (bx >= 512) {                 // ---- L transpose-cast ----
        auto ts = reinterpret_cast<__bf16(*)[72]>(smraw);
        const int b2 = bx - 512;
        const int r0 = (b2 & 15) * 64;
        const int c0 = (b2 >> 4) * 64;
        const int r = t >> 2, cb = (t & 3) * 16;
        const float* sp = L + (size_t)(r0 + r) * SEQ + c0 + cb;
        #pragma unroll
        for (int u = 0; u < 4; ++u) {
            const float4 v = *reinterpret_cast<const float4*>(sp + u * 4);
            ts[r][cb + u*4 + 0] = (__bf16)v.x;
            ts[r][cb + u*4 + 1] = (__bf16)v.y;
            ts[r][cb + u*4 + 2] = (__bf16)v.z;
            ts[r][cb + u*4 + 3] = (__bf16)v.w;
        }
        __syncthreads();
        const int dl = t >> 2, kb = (t & 3) * 16;
        bfx8 o0, o1;
        #pragma unroll
        for (int e = 0; e < 8; ++e) { o0[e] = ts[kb + e][dl]; o1[e] = ts[kb + 8 + e][dl]; }
        __bf16* dp = Lt + (size_t)(c0 + dl) * SEQ + r0 + kb;
        *reinterpret_cast<bfx8*>(dp)     = o0;
        *reinterpret_cast<bfx8*>(dp + 8) = o1;
        return;
    }

    // ---- GEMM1: tile 64x64x64, dbuf, 2x2 wave tiling, fp32 LDS + in-reg cvt ----
    float* AsP = reinterpret_cast<float*>(smraw);            // [2][4096]
    float* BsP = reinterpret_cast<float*>(smraw + 32768);    // [2][4096]
    const int m0 = (bx & 127) * 64;
    const int n0 = (bx >> 7) * 64;
    const int l = t & 63, w = t >> 6;
    const int wm = w >> 1, wn = w & 1;

    f32v4 acc[2][2] = {};

    auto stage = [&](int buf, int k0) {
        #pragma unroll
        for (int q = 0; q < 4; ++q) {
            const int p   = 4 * w + q;               // 1KB page (4 rows)
            const int row = p * 4 + (l >> 4);
            const int cs  = (l & 15) ^ (row & 15);   // pre-swizzled source chunk
            gll16(X  + (size_t)(m0 + row) * 256 + k0 + cs * 4, &AsP[buf*4096 + p*256]);
            gll16(Mw + (size_t)(n0 + row) * 256 + k0 + cs * 4, &BsP[buf*4096 + p*256]);
        }
    };

    stage(0, 0);
    int cur = 0;
    #pragma unroll
    for (int ts_ = 0; ts_ < 4; ++ts_) {
        __syncthreads();
        if (ts_ < 3) stage(cur ^ 1, (ts_ + 1) * 64);
        #pragma unroll
        for (int ks = 0; ks < 2; ++ks) {
            const int c0 = ks * 8 + (l >> 4) * 2;
            const int r15 = l & 15;
            bfx8 af[2], bfr[2];
            #pragma unroll
            for (int i = 0; i < 2; ++i) {
                const int Ra = 32 * wm + 16 * i + (l & 15);
                const float4 f0 = *reinterpret_cast<const float4*>(&AsP[cur*4096 + Ra*64 + (( c0      ^ r15) << 2)]);
                const float4 f1 = *reinterpret_cast<const float4*>(&AsP[cur*4096 + Ra*64 + (((c0 + 1) ^ r15) << 2)]);
                af[i][0]=(__bf16)f0.x; af[i][1]=(__bf16)f0.y; af[i][2]=(__bf16)f0.z; af[i][3]=(__bf16)f0.w;
                af[i][4]=(__bf16)f1.x; af[i][5]=(__bf16)f1.y; af[i][6]=(__bf16)f1.z; af[i][7]=(__bf16)f1.w;
                const int Rb = 32 * wn + 16 * i + (l & 15);
                const float4 g0 = *reinterpret_cast<const float4*>(&BsP[cur*4096 + Rb*64 + (( c0      ^ r15) << 2)]);
                const float4 g1 = *reinterpret_cast<const float4*>(&BsP[cur*4096 + Rb*64 + (((c0 + 1) ^ r15) << 2)]);
                bfr[i][0]=(__bf16)g0.x; bfr[i][1]=(__bf16)g0.y; bfr[i][2]=(__bf16)g0.z; bfr[i][3]=(__bf16)g0.w;
                bfr[i][4]=(__bf16)g1.x; bfr[i][5]=(__bf16)g1.y; bfr[i][6]=(__bf16)g1.z; bfr[i][7]=(__bf16)g1.w;
            }
            #pragma unroll
            for (int i = 0; i < 2; ++i)
                #pragma unroll
                for (int j = 0; j < 2; ++j)
                    acc[i][j] = __builtin_amdgcn_mfma_f32_16x16x32_bf16(af[i], bfr[j], acc[i][j], 0, 0, 0);
        }
        cur ^= 1;
    }

    const int col = l & 15;
    #pragma unroll
    for (int i = 0; i < 2; ++i)
        #pragma unroll
        for (int j = 0; j < 2; ++j)
            #pragma unroll
            for (int r = 0; r < 4; ++r)
                Zl[(size_t)(m0 + 32*wm + 16*i + 4*(l >> 4) + r) * 256 + n0 + 32*wn + 16*j + col]
                    = (__bf16)acc[i][j][r];
}

// ---------------------------------------------------------------------------
// K2: gate via MFMA. block = one k. LN rows in LDS, W synthesized in regs.
// ---------------------------------------------------------------------------
__global__ void __launch_bounds__(256, 4)
k_gateM(const __bf16* __restrict__ Zl, const __bf16* __restrict__ Pb,
        const float* __restrict__ gamma, const float* __restrict__ beta,
        __bf16* __restrict__ V)
{
    __shared__ __bf16 zraw[8 * 256];
    __shared__ __bf16 znorm[16 * 256];
    __shared__ float mu_s[8], rs_s[8];

    const int k = blockIdx.x;
    const int t = threadIdx.x;
    const int l = t & 63, w = t >> 6;

    const int m  = t >> 5;
    const int ch = t & 31;
    const bfx8 zv = *reinterpret_cast<const bfx8*>(Zl + ((size_t)(m * SEQ + k)) * DIM + ch * 8);
    *reinterpret_cast<bfx8*>(&zraw[m * 256 + ((ch ^ m) << 3)]) = zv;

    bfx8 zz;
    #pragma unroll
    for (int e = 0; e < 8; ++e) zz[e] = (__bf16)0.f;
    *reinterpret_cast<bfx8*>(&znorm[(8 + m) * 256 + ((ch ^ m) << 3)]) = zz;

    float s1 = 0.f, s2 = 0.f;
    #pragma unroll
    for (int e = 0; e < 8; ++e) { const float v = (float)zv[e]; s1 += v; s2 += v * v; }
    #pragma unroll
    for (int q = 16; q >= 1; q >>= 1) { s1 += __shfl_xor(s1, q); s2 += __shfl_xor(s2, q); }
    if (ch == 0) {
        const float mu  = s1 * (1.f / DIM);
        const float var = s2 * (1.f / DIM) - mu * mu;
        mu_s[m] = mu;
        rs_s[m] = rsqrtf(var + LN_EPS_C);
    }
    __syncthreads();

    {
        const float mu = mu_s[m], rs = rs_s[m];
        const float4 g0 = *reinterpret_cast<const float4*>(gamma + ch * 8);
        const float4 g1 = *reinterpret_cast<const float4*>(gamma + ch * 8 + 4);
        const float4 b0 = *reinterpret_cast<const float4*>(beta  + ch * 8);
        const float4 b1 = *reinterpret_cast<const float4*>(beta  + ch * 8 + 4);
        const float gv[8] = {g0.x, g0.y, g0.z, g0.w, g1.x, g1.y, g1.z, g1.w};
        const float bv[8] = {b0.x, b0.y, b0.z, b0.w, b1.x, b1.y, b1.z, b1.w};
        bfx8 nv;
        #pragma unroll
        for (int e = 0; e < 8; ++e)
            nv[e] = (__bf16)(((float)zv[e] - mu) * rs * gv[e] + bv[e]);
        *reinterpret_cast<bfx8*>(&znorm[m * 256 + ((ch ^ m) << 3)]) = nv;
    }
    __syncthreads();

    const int mm = l & 15;
    bfx8 af[8];
    #pragma unroll
    for (int ks = 0; ks < 8; ++ks) {
        const int cc = ks * 4 + (l >> 4);
        af[ks] = *reinterpret_cast<const bfx8*>(&znorm[mm * 256 + ((cc ^ (mm & 7)) << 3)]);
    }

    const float kf = (float)k;
    const int n0w = w * 64;
    f32v4 acc[4] = {};
    #pragma unroll
    for (int c = 0; c < 4; ++c) {
        const int i = n0w + 16 * c + (l & 15);
        const __bf16* Prow = Pb + (size_t)i * DIM;
        #pragma unroll
        for (int ks = 0; ks < 8; ++ks) {
            const int jb = ks * 32 + (l >> 4) * 8;
            const bfx8 pv = *reinterpret_cast<const bfx8*>(Prow + jb);
            const float pbase = (float)(i * DIM + jb + 2);
            bfx8 wf;
            #pragma unroll
            for (int e = 0; e < 8; ++e) {
                float r = kf * __builtin_amdgcn_rcpf(pbase + (float)e);
                r = __builtin_amdgcn_fractf(r);       // revolutions in [0,1)
                wf[e] = (__bf16)(__builtin_amdgcn_cosf(r) * (float)pv[e]);
            }
            acc[c] = __builtin_amdgcn_mfma_f32_16x16x32_bf16(af[ks], wf, acc[c], 0, 0, 0);
        }
    }

    const int g = l >> 4;
    if (g < 2) {
        const int col = l & 15;
        #pragma unroll
        for (int c = 0; c < 4; ++c) {
            const int i = n0w + 16 * c + col;
            #pragma unroll
            for (int r = 0; r < 4; ++r) {
                const int b = 4 * g + r;
                const float resid = (float)zraw[b * 256 + (((i >> 3) ^ b) << 3) + (i & 7)];
                V[((size_t)(b * SEQ + k)) * DIM + i] = (__bf16)(acc[c][r] + resid);
            }
        }
    }
}

// ---------------------------------------------------------------------------
// K3: V[b][k][d] -> Vt[b][d][k]  (bf16, 64x64 tiles)
// ---------------------------------------------------------------------------
__global__ void __launch_bounds__(256)
k_transV(const __bf16* __restrict__ src, __bf16* __restrict__ dst)
{
    __shared__ __bf16 ts[64][72];
    const long z = blockIdx.z;
    const int r0 = blockIdx.x * 64;   // k
    const int c0 = blockIdx.y * 64;   // d
    const int t  = threadIdx.x;
    const int r  = t >> 2, cb = (t & 3) * 16;

    const __bf16* sp = src + z * (SEQ * DIM) + (size_t)(r0 + r) * DIM + c0 + cb;
    #pragma unroll
    for (int u = 0; u < 2; ++u) {
        const bfx8 v = *reinterpret_cast<const bfx8*>(sp + u * 8);
        #pragma unroll
        for (int e = 0; e < 8; ++e) ts[r][cb + u*8 + e] = v[e];
    }
    __syncthreads();

    const int dl = t >> 2, kb = (t & 3) * 16;
    bfx8 o0, o1;
    #pragma unroll
    for (int e = 0; e < 8; ++e) { o0[e] = ts[kb + e][dl]; o1[e] = ts[kb + 8 + e][dl]; }
    __bf16* dp = dst + z * (SEQ * DIM) + (size_t)(c0 + dl) * SEQ + r0 + kb;
    *reinterpret_cast<bfx8*>(dp)     = o0;
    *reinterpret_cast<bfx8*>(dp + 8) = o1;
}

// ---------------------------------------------------------------------------
// K4: out[b][s][d] = sum_k Lt[s][k] * Vt[b][d][k]  (fp32 out)
// Tile 64x64 x BK=128, double-buffered, 1 barrier per 128-K (8 phases),
// 2x2 wave tiling.  LDS rows = 256B = 16 chunks; chunk c of row r stored
// at c^(r&15) (both-sides swizzle via pre-swizzled gll source).
// ---------------------------------------------------------------------------
__global__ void __launch_bounds__(256)
k_gemm2(const __bf16* __restrict__ A, const __bf16* __restrict__ Bt,
        float* __restrict__ C)
{
    __shared__ __bf16 As[2][64 * 128];
    __shared__ __bf16 Bs[2][64 * 128];
    const int m0 = blockIdx.x * 64;   // s
    const int n0 = blockIdx.y * 64;   // d
    const long zb = blockIdx.z;
    const int t = threadIdx.x, l = t & 63, w = t >> 6;
    const int wm = w >> 1, wn = w & 1;
    const __bf16* Bz = Bt + zb * (SEQ * DIM);

    f32v4 acc[2][2] = {};

    auto stage = [&](int buf, int k0) {
        #pragma unroll
        for (int q = 0; q < 4; ++q) {
            const int p   = 4 * w + q;             // 16 pages x (4 rows of 256B)
            const int row = p * 4 + (l >> 4);
            const int sc  = (l & 15) ^ (row & 15); // pre-swizzled source chunk
            gll16(A  + (size_t)(m0 + row) * SEQ + k0 + sc * 8, &As[buf][p * 512]);
            gll16(Bz + (size_t)(n0 + row) * SEQ + k0 + sc * 8, &Bs[buf][p * 512]);
        }
    };

    stage(0, 0);
    int cur = 0;
    #pragma unroll
    for (int ts_ = 0; ts_ < 8; ++ts_) {
        __syncthreads();                      // drain stage(ts_)
        if (ts_ < 7) stage(cur ^ 1, (ts_ + 1) * 128);
        #pragma unroll
        for (int ks = 0; ks < 4; ++ks) {
            const int lch = ks * 4 + (l >> 4);        // logical 16B chunk 0..15
            bfx8 af[2], bfr[2];
            #pragma unroll
            for (int i = 0; i < 2; ++i) {
                const int Ra = 32 * wm + 16 * i + (l & 15);
                af[i]  = *reinterpret_cast<const bfx8*>(&As[cur][Ra * 128 + ((lch ^ (Ra & 15)) << 3)]);
                const int Rb = 32 * wn + 16 * i + (l & 15);
                bfr[i] = *reinterpret_cast<const bfx8*>(&Bs[cur][Rb * 128 + ((lch ^ (Rb & 15)) << 3)]);
            }
            #pragma unroll
            for (int i = 0; i < 2; ++i)
                #pragma unroll
                for (int j = 0; j < 2; ++j)
                    acc[i][j] = __builtin_amdgcn_mfma_f32_16x16x32_bf16(af[i], bfr[j], acc[i][j], 0, 0, 0);
        }
        cur ^= 1;
    }

    const int col = l & 15;
    #pragma unroll
    for (int i = 0; i < 2; ++i)
        #pragma unroll
        for (int j = 0; j < 2; ++j)
            #pragma unroll
            for (int r = 0; r < 4; ++r)
                C[zb * (size_t)(SEQ * DIM)
                  + (size_t)(m0 + 32*wm + 16*i + 4*(l >> 4) + r) * 256
                  + n0 + 32*wn + 16*j + col] = acc[i][j][r];
}

// ---------------------------------------------------------------------------
extern "C" void kernel_launch(void* const* d_in, const int* in_sizes, int n_in,
                              void* d_out, int out_size, void* d_ws, size_t ws_size,
                              hipStream_t stream)
{
    const float* x     = (const float*)d_in[0];
    const float* M     = (const float*)d_in[1];
    const float* P     = (const float*)d_in[2];
    const float* L     = (const float*)d_in[3];
    const float* gamma = (const float*)d_in[4];
    const float* beta  = (const float*)d_in[5];
    float* out = (float*)d_out;

    char* ws = (char*)d_ws;
    __bf16* Pb = (__bf16*)(ws);                              // 128 KB [256][256]
    __bf16* Lt = (__bf16*)(ws + (128u << 10));               // 2 MB   [1024 s][1024 k]
    __bf16* Zl = (__bf16*)(ws + (2u << 20) + (128u << 10));  // 4 MB   [8192][256]
    __bf16* V  = (__bf16*)(ws + (6u << 20) + (128u << 10));  // 4 MB   [b][k][d]
    __bf16* Vt = (__bf16*)(ws + (10u << 20) + (128u << 10)); // 4 MB   [b][d][k]

    // K1: prep (L-transpose + P-cast) + GEMM1
    hipLaunchKernelGGL(k_pg1, dim3(832), dim3(256), 0, stream,
                       x, M, L, P, Zl, Lt, Pb);

    // K2: LN + cos-gated MFMA + residual -> V bf16
    hipLaunchKernelGGL(k_gateM, dim3(SEQ), dim3(256), 0, stream,
                       Zl, Pb, gamma, beta, V);

    // K3: V -> Vt
    hipLaunchKernelGGL(k_transV, dim3(16, 4, 8), dim3(256), 0, stream, V, Vt);

    // K4: out = Lt @ Vt^T per batch (BK=128, 8 phases)
    hipLaunchKernelGGL(k_gemm2, dim3(16, 4, 8), dim3(256), 0, stream, Lt, Vt, out);
}